// Round 21
// baseline (421.944 us; speedup 1.0000x reference)
//
#include <hip/hip_runtime.h>
#include <hip/hip_bf16.h>
#include <math.h>

#define BB 64
#define JJ 16384
#define DD 32
#define HH 128
#define WW 4
#define EHH 256
#define CHUNK 64
#define CPB 16
#define NBLK 16              /* JJ/(CHUNK*CPB) */
#define NPART (NBLK * 4)     /* per-wave partials */
#define PART_STRIDE 136
#define LN_EPS 1e-5f
#define HPRE_OFF  (4 << 20)                 /* part: 2.23MB at 0 */
#define HSTAT_OFF (HPRE_OFF + JJ*HH*4)      /* hpre: 8.39MB */
#define SQ_OFF    (HSTAT_OFF + JJ*16)       /* hstat: 256KB */

typedef float vf4 __attribute__((ext_vector_type(4)));

#define FMAQ(acc,B,q,f) \
  acc[B+0]=fmaf((q).x,f,acc[B+0]); acc[B+1]=fmaf((q).y,f,acc[B+1]); \
  acc[B+2]=fmaf((q).z,f,acc[B+2]); acc[B+3]=fmaf((q).w,f,acc[B+3]);

#define S2FMA(wq,h0,h1) \
  ac0[0]=fmaf(h0,(wq).x,ac0[0]); ac1[0]=fmaf(h1,(wq).x,ac1[0]); \
  ac0[1]=fmaf(h0,(wq).y,ac0[1]); ac1[1]=fmaf(h1,(wq).y,ac1[1]); \
  ac0[2]=fmaf(h0,(wq).z,ac0[2]); ac1[2]=fmaf(h1,(wq).z,ac1[2]); \
  ac0[3]=fmaf(h0,(wq).w,ac0[3]); ac1[3]=fmaf(h1,(wq).w,ac1[3]);

// ---- Kernel 0: hpre' = feat @ w1[1:,:] + b1  AND per-row LN1 stats ----
__global__ void pe_k0(const float* __restrict__ feat, const float* __restrict__ w1,
                      const float* __restrict__ b1,
                      float* __restrict__ hpre, float4* __restrict__ hstat4)
{
    const int tid = threadIdx.x;
    const int row = blockIdx.x * 32 + (tid >> 3);
    const int sg = tid & 7;
    float acc[16];
    #pragma unroll
    for (int o = 0; o < 16; ++o) acc[o] = 0.f;
    const float* fr = feat + (size_t)row * 32;
    const float* w1s = w1 + sg * 16;
    #pragma unroll 4
    for (int k = 0; k < 32; ++k) {
        const float f = fr[k];
        const float* wr = w1s + (k + 1) * HH;
        const float4 q0 = *(const float4*)(wr);
        const float4 q1 = *(const float4*)(wr + 4);
        const float4 q2 = *(const float4*)(wr + 8);
        const float4 q3 = *(const float4*)(wr + 12);
        FMAQ(acc,0,q0,f) FMAQ(acc,4,q1,f) FMAQ(acc,8,q2,f) FMAQ(acc,12,q3,f)
    }
    #pragma unroll
    for (int i = 0; i < 4; ++i) {
        const float4 bq = *(const float4*)(b1 + sg*16 + 4*i);
        acc[4*i+0]+=bq.x; acc[4*i+1]+=bq.y; acc[4*i+2]+=bq.z; acc[4*i+3]+=bq.w;
    }
    float s0p=0.f, q0p=0.f, q1p=0.f;
    #pragma unroll
    for (int o = 0; o < 16; ++o) {
        s0p += acc[o];
        q0p = fmaf(acc[o], acc[o], q0p);
        q1p = fmaf(acc[o], w1s[o], q1p);   // w1 row 0 (x-weights)
    }
    #pragma unroll
    for (int st = 1; st < 8; st <<= 1) {
        s0p += __shfl_xor(s0p, st, 64);
        q0p += __shfl_xor(q0p, st, 64);
        q1p += __shfl_xor(q1p, st, 64);
    }
    if (sg == 0) hstat4[row] = make_float4(s0p, q0p, q1p, 0.f);

    float4* op = (float4*)(hpre + (size_t)row * HH + sg * 16);
    op[0] = make_float4(acc[0],acc[1],acc[2],acc[3]);
    op[1] = make_float4(acc[4],acc[5],acc[6],acc[7]);
    op[2] = make_float4(acc[8],acc[9],acc[10],acc[11]);
    op[3] = make_float4(acc[12],acc[13],acc[14],acc[15]);
}

// ---- Kernel 0s: scalars S1 = Σ w1[0,:], Q2 = Σ w1[0,:]^2 ----
__global__ void pe_k0s(const float* __restrict__ w1, float* __restrict__ sq)
{
    const int t = threadIdx.x;   // 128
    float w = w1[t];
    float s = w, q = w * w;
    #pragma unroll
    for (int st = 1; st < 64; st <<= 1) {
        s += __shfl_xor(s, st, 64);
        q += __shfl_xor(q, st, 64);
    }
    __shared__ float ls[4];
    if ((t & 63) == 0) { ls[(t>>6)*2] = s; ls[(t>>6)*2+1] = q; }
    __syncthreads();
    if (t == 0) { sq[0] = ls[0] + ls[2]; sq[1] = ls[1] + ls[3]; }
}

// ---------------- Kernel 1 ----------------
// R19 champion (331us) + pipe rebalancing: the DS pipe was ~90% saturated
// (160 b128 reads + ~60 shfl per wave-chunk) while VALU sat at 50%.
// (1) hpre loads are NONTEMPORAL (ext_vector_type works with the builtin;
//     the 32KB/chunk stream no longer evicts L1), so
// (2) stage-2 weight reads split 50/50: e=0,1 from w2l (DS pipe),
//     e=2,3 from global w2 (TA pipe, L1-resident). DS load -27%.
__launch_bounds__(256, 2)
__global__ void pe_k1(const float* __restrict__ x, const int* __restrict__ mask,
                      const float* __restrict__ hpre,
                      const float4* __restrict__ hstat4, const float* __restrict__ sq,
                      const float* __restrict__ w1,
                      const float* __restrict__ ln1g, const float* __restrict__ ln1b,
                      const float* __restrict__ w2, const float* __restrict__ b2,
                      const float* __restrict__ ln2g, const float* __restrict__ ln2b,
                      const float* __restrict__ gw1, const float* __restrict__ gb1,
                      const float* __restrict__ gw2, const float* __restrict__ gb2,
                      float* __restrict__ part)
{
    const int tid = threadIdx.x;
    const int cb = blockIdx.x, b = blockIdx.y;
    const int rg = tid >> 3, sg = tid & 7;
    const int r0 = rg * 2, r1 = r0 + 1;
    const int wv = tid >> 6, lane = tid & 63;

    __shared__ float4 uni[CHUNK * 17];    // hk4 (cols 0..15) / holds (cols 0..7)
    __shared__ float4 p_lds4[CHUNK];      // softmax numerators (4 heads)
    __shared__ float4 w2l[HH * 8];        // w2 staged: f4 idx = k*8 + dquad (16KB)

    const int ad = lane & 31, half = lane >> 5;
    const int wa = half, wb = half + 2;
    const int rbase = wv * 16;

    float m_run_a = -1e30f, s_run_a = 0.f, accr_a = 0.f;
    float m_run_b = -1e30f, s_run_b = 0.f, accr_b = 0.f;

    const float* w1s = w1 + sg * 16;
    const float S1v = sq[0], Q2v = sq[1];

    // ---- preload w2 into LDS (once per block) ----
    {
        const float4* w2g = (const float4*)w2;
        #pragma unroll
        for (int i = 0; i < 4; ++i) w2l[tid + i*256] = w2g[tid + i*256];
    }
    __syncthreads();

    for (int ch = 0; ch < CPB; ++ch) {
        const int jbase = (cb * CPB + ch) * CHUNK;

        // ---- stage 1: hb = hpre' + x*w1[0] (b1 folded; NT loads) ----
        float hb0[16], hb1[16];
        const float2 xq = *(const float2*)(x + (size_t)b * JJ + jbase + r0);
        {
            const vf4* hp4 = (const vf4*)(hpre + (size_t)jbase * HH);
            #pragma unroll
            for (int i = 0; i < 4; ++i) {
                const vf4 h0q = __builtin_nontemporal_load(&hp4[r0*32 + sg*4 + i]);
                const vf4 h1q = __builtin_nontemporal_load(&hp4[r1*32 + sg*4 + i]);
                const float4 wq = *(const float4*)(w1s + 4*i);
                hb0[4*i+0] = fmaf(wq.x, xq.x, h0q.x);
                hb0[4*i+1] = fmaf(wq.y, xq.x, h0q.y);
                hb0[4*i+2] = fmaf(wq.z, xq.x, h0q.z);
                hb0[4*i+3] = fmaf(wq.w, xq.x, h0q.w);
                hb1[4*i+0] = fmaf(wq.x, xq.y, h1q.x);
                hb1[4*i+1] = fmaf(wq.y, xq.y, h1q.y);
                hb1[4*i+2] = fmaf(wq.z, xq.y, h1q.z);
                hb1[4*i+3] = fmaf(wq.w, xq.y, h1q.w);
            }
        }
        // ---- LN1 + relu via closed-form stats (no butterfly) ----
        {
            const float4 st0 = hstat4[jbase + r0];
            const float4 st1 = hstat4[jbase + r1];
            const float mu0 = (st0.x + xq.x * S1v) * (1.f/HH);
            const float e20 = (st0.y + 2.f*xq.x*st0.z + xq.x*xq.x*Q2v) * (1.f/HH);
            const float rs0 = rsqrtf(fmaxf(e20 - mu0*mu0, 0.f) + LN_EPS);
            const float mu1 = (st1.x + xq.y * S1v) * (1.f/HH);
            const float e21 = (st1.y + 2.f*xq.y*st1.z + xq.y*xq.y*Q2v) * (1.f/HH);
            const float rs1 = rsqrtf(fmaxf(e21 - mu1*mu1, 0.f) + LN_EPS);
            #pragma unroll
            for (int q4 = 0; q4 < 4; ++q4) {
                const float4 gq = *(const float4*)(ln1g + sg*16 + q4*4);
                const float4 tq = *(const float4*)(ln1b + sg*16 + q4*4);
                hb0[q4*4+0]=fmaxf(fmaf((hb0[q4*4+0]-mu0)*rs0, gq.x, tq.x),0.f);
                hb0[q4*4+1]=fmaxf(fmaf((hb0[q4*4+1]-mu0)*rs0, gq.y, tq.y),0.f);
                hb0[q4*4+2]=fmaxf(fmaf((hb0[q4*4+2]-mu0)*rs0, gq.z, tq.z),0.f);
                hb0[q4*4+3]=fmaxf(fmaf((hb0[q4*4+3]-mu0)*rs0, gq.w, tq.w),0.f);
                hb1[q4*4+0]=fmaxf(fmaf((hb1[q4*4+0]-mu1)*rs1, gq.x, tq.x),0.f);
                hb1[q4*4+1]=fmaxf(fmaf((hb1[q4*4+1]-mu1)*rs1, gq.y, tq.y),0.f);
                hb1[q4*4+2]=fmaxf(fmaf((hb1[q4*4+2]-mu1)*rs1, gq.z, tq.z),0.f);
                hb1[q4*4+3]=fmaxf(fmaf((hb1[q4*4+3]-mu1)*rs1, gq.w, tq.w),0.f);
            }
        }

        // ---- stage 2: two K-halves via uni; weights split LDS/global ----
        float ac0[4] = {0.f,0.f,0.f,0.f}, ac1[4] = {0.f,0.f,0.f,0.f};
        #pragma unroll
        for (int hf2 = 0; hf2 < 2; ++hf2) {
            if ((sg >> 2) == hf2) {                 // owners publish this half
                const int sgl = sg & 3;
                #pragma unroll
                for (int o4 = 0; o4 < 4; ++o4) {
                    const int p = (sgl*4 + o4 + rg) & 15;
                    uni[r0*17 + p] = make_float4(hb0[o4*4],hb0[o4*4+1],hb0[o4*4+2],hb0[o4*4+3]);
                    uni[r1*17 + p] = make_float4(hb1[o4*4],hb1[o4*4+1],hb1[o4*4+2],hb1[o4*4+3]);
                }
            }
            // same-wave producer/consumer: DS pipe is in-order, no barrier
            #pragma unroll 4
            for (int L = 0; L < 16; ++L) {
                const int p = (L + rg) & 15;
                const float4 h0q = uni[r0*17 + p];
                const float4 h1q = uni[r1*17 + p];
                const int kb = hf2*64 + L*4;
                const float* w2g = w2 + (size_t)kb*DD + sg*4;
                {   // e=0: LDS
                    const float4 wq = w2l[(kb + 0)*8 + sg];
                    S2FMA(wq, h0q.x, h1q.x)
                }
                {   // e=1: LDS
                    const float4 wq = w2l[(kb + 1)*8 + sg];
                    S2FMA(wq, h0q.y, h1q.y)
                }
                {   // e=2: global (L1)
                    const float4 wq = *(const float4*)(w2g + 2*DD);
                    S2FMA(wq, h0q.z, h1q.z)
                }
                {   // e=3: global (L1)
                    const float4 wq = *(const float4*)(w2g + 3*DD);
                    S2FMA(wq, h0q.w, h1q.w)
                }
            }
        }
        {
            const float4 bq = *(const float4*)(b2 + sg*4);
            ac0[0]+=bq.x; ac0[1]+=bq.y; ac0[2]+=bq.z; ac0[3]+=bq.w;
            ac1[0]+=bq.x; ac1[1]+=bq.y; ac1[2]+=bq.z; ac1[3]+=bq.w;
        }
        // ---- LN2 + relu -> holds (cols 0..7 of uni; hk4 data dead now) ----
        {
            float s0 = ac0[0]+ac0[1]+ac0[2]+ac0[3];
            float s1 = ac1[0]+ac1[1]+ac1[2]+ac1[3];
            float q0 = ac0[0]*ac0[0]+ac0[1]*ac0[1]+ac0[2]*ac0[2]+ac0[3]*ac0[3];
            float q1 = ac1[0]*ac1[0]+ac1[1]*ac1[1]+ac1[2]*ac1[2]+ac1[3]*ac1[3];
            #pragma unroll
            for (int st = 1; st < 8; st <<= 1) {
                s0 += __shfl_xor(s0, st, 64); q0 += __shfl_xor(q0, st, 64);
                s1 += __shfl_xor(s1, st, 64); q1 += __shfl_xor(q1, st, 64);
            }
            const float mu0 = s0 * (1.f/DD);
            const float rs0 = rsqrtf(fmaxf(q0*(1.f/DD) - mu0*mu0, 0.f) + LN_EPS);
            const float mu1 = s1 * (1.f/DD);
            const float rs1 = rsqrtf(fmaxf(q1*(1.f/DD) - mu1*mu1, 0.f) + LN_EPS);
            const float4 gq = *(const float4*)(ln2g + sg*4);
            const float4 tq = *(const float4*)(ln2b + sg*4);
            uni[r0*17 + sg] = make_float4(
                fmaxf(fmaf((ac0[0]-mu0)*rs0, gq.x, tq.x),0.f),
                fmaxf(fmaf((ac0[1]-mu0)*rs0, gq.y, tq.y),0.f),
                fmaxf(fmaf((ac0[2]-mu0)*rs0, gq.z, tq.z),0.f),
                fmaxf(fmaf((ac0[3]-mu0)*rs0, gq.w, tq.w),0.f));
            uni[r1*17 + sg] = make_float4(
                fmaxf(fmaf((ac1[0]-mu1)*rs1, gq.x, tq.x),0.f),
                fmaxf(fmaf((ac1[1]-mu1)*rs1, gq.y, tq.y),0.f),
                fmaxf(fmaf((ac1[2]-mu1)*rs1, gq.z, tq.z),0.f),
                fmaxf(fmaf((ac1[3]-mu1)*rs1, gq.w, tq.w),0.f));
        }

        // ---- stage 3 (remapped): lane computes o={2sg,2sg+1} over full K=32 ----
        float g1r0[2] = {0.f, 0.f}, g1r1[2] = {0.f, 0.f};
        #pragma unroll
        for (int k4 = 0; k4 < 8; ++k4) {
            const float4 h0q = uni[r0*17 + k4];
            const float4 h1q = uni[r1*17 + k4];
            const float h0a = h0q.x, h0b = h0q.y, h0c = h0q.z, h0d = h0q.w;
            const float h1a = h1q.x, h1b = h1q.y, h1c = h1q.z, h1d = h1q.w;
            const float2 w0 = *(const float2*)(gw1 + (k4*4+0)*16 + sg*2);
            const float2 w1q = *(const float2*)(gw1 + (k4*4+1)*16 + sg*2);
            const float2 w2q = *(const float2*)(gw1 + (k4*4+2)*16 + sg*2);
            const float2 w3q = *(const float2*)(gw1 + (k4*4+3)*16 + sg*2);
            g1r0[0]=fmaf(h0a,w0.x,g1r0[0]); g1r0[1]=fmaf(h0a,w0.y,g1r0[1]);
            g1r1[0]=fmaf(h1a,w0.x,g1r1[0]); g1r1[1]=fmaf(h1a,w0.y,g1r1[1]);
            g1r0[0]=fmaf(h0b,w1q.x,g1r0[0]); g1r0[1]=fmaf(h0b,w1q.y,g1r0[1]);
            g1r1[0]=fmaf(h1b,w1q.x,g1r1[0]); g1r1[1]=fmaf(h1b,w1q.y,g1r1[1]);
            g1r0[0]=fmaf(h0c,w2q.x,g1r0[0]); g1r0[1]=fmaf(h0c,w2q.y,g1r0[1]);
            g1r1[0]=fmaf(h1c,w2q.x,g1r1[0]); g1r1[1]=fmaf(h1c,w2q.y,g1r1[1]);
            g1r0[0]=fmaf(h0d,w3q.x,g1r0[0]); g1r0[1]=fmaf(h0d,w3q.y,g1r0[1]);
            g1r1[0]=fmaf(h1d,w3q.x,g1r1[0]); g1r1[1]=fmaf(h1d,w3q.y,g1r1[1]);
        }
        {
            const float2 gbq = *(const float2*)(gb1 + sg*2);
            g1r0[0]=fmaxf(g1r0[0]+gbq.x,0.f); g1r0[1]=fmaxf(g1r0[1]+gbq.y,0.f);
            g1r1[0]=fmaxf(g1r1[0]+gbq.x,0.f); g1r1[1]=fmaxf(g1r1[1]+gbq.y,0.f);
        }

        // ---- stage 4: partial over own 2 o, butterfly over sg, bias+clip ----
        float l0[4], l1[4];
        {
            const float4 w0q = *(const float4*)(gw2 + (sg*2)*4);
            const float4 w1q = *(const float4*)(gw2 + (sg*2+1)*4);
            l0[0]=fmaf(g1r0[0],w0q.x, g1r0[1]*w1q.x);
            l0[1]=fmaf(g1r0[0],w0q.y, g1r0[1]*w1q.y);
            l0[2]=fmaf(g1r0[0],w0q.z, g1r0[1]*w1q.z);
            l0[3]=fmaf(g1r0[0],w0q.w, g1r0[1]*w1q.w);
            l1[0]=fmaf(g1r1[0],w0q.x, g1r1[1]*w1q.x);
            l1[1]=fmaf(g1r1[0],w0q.y, g1r1[1]*w1q.y);
            l1[2]=fmaf(g1r1[0],w0q.z, g1r1[1]*w1q.z);
            l1[3]=fmaf(g1r1[0],w0q.w, g1r1[1]*w1q.w);
            #pragma unroll
            for (int st = 1; st < 8; st <<= 1) {
                #pragma unroll
                for (int w = 0; w < 4; ++w) {
                    l0[w] += __shfl_xor(l0[w], st, 64);
                    l1[w] += __shfl_xor(l1[w], st, 64);
                }
            }
            const float4 gbq = *(const float4*)gb2;
            l0[0] = fminf(fmaxf(l0[0]+gbq.x, -10.f), 10.f);
            l0[1] = fminf(fmaxf(l0[1]+gbq.y, -10.f), 10.f);
            l0[2] = fminf(fmaxf(l0[2]+gbq.z, -10.f), 10.f);
            l0[3] = fminf(fmaxf(l0[3]+gbq.w, -10.f), 10.f);
            l1[0] = fminf(fmaxf(l1[0]+gbq.x, -10.f), 10.f);
            l1[1] = fminf(fmaxf(l1[1]+gbq.y, -10.f), 10.f);
            l1[2] = fminf(fmaxf(l1[2]+gbq.z, -10.f), 10.f);
            l1[3] = fminf(fmaxf(l1[3]+gbq.w, -10.f), 10.f);
        }

        // ---- wave-local masked max (stages 8/16/32) ----
        const int2 mq = *(const int2*)(mask + (size_t)b * JJ + jbase + r0);
        const float mk0 = mq.x ? 1.f : 0.f, mk1 = mq.y ? 1.f : 0.f;
        float lm[4];
        #pragma unroll
        for (int w = 0; w < 4; ++w)
            lm[w] = fmaxf(mk0 > 0.f ? l0[w] : -1e30f,
                          mk1 > 0.f ? l1[w] : -1e30f);
        #pragma unroll
        for (int st = 8; st < 64; st <<= 1) {
            #pragma unroll
            for (int w = 0; w < 4; ++w)
                lm[w] = fmaxf(lm[w], __shfl_xor(lm[w], st, 64));
        }

        // ---- p = mask*exp(l - m_wave); publish (sg==0); wave-local sums ----
        float ps[4];
        {
            float p0v[4], p1v[4];
            #pragma unroll
            for (int w = 0; w < 4; ++w) {
                p0v[w] = mk0 * __expf(fminf(l0[w] - lm[w], 0.f));
                p1v[w] = mk1 * __expf(fminf(l1[w] - lm[w], 0.f));
                ps[w] = p0v[w] + p1v[w];
            }
            if (sg == 0) {
                p_lds4[r0] = make_float4(p0v[0],p0v[1],p0v[2],p0v[3]);
                p_lds4[r1] = make_float4(p1v[0],p1v[1],p1v[2],p1v[3]);
            }
            #pragma unroll
            for (int st = 8; st < 64; st <<= 1) {
                #pragma unroll
                for (int w = 0; w < 4; ++w) ps[w] += __shfl_xor(ps[w], st, 64);
            }
        }

        // ---- wave-local weighted-sum accumulate with online merge ----
        {
            float dota = 0.f, dotb = 0.f;
            #pragma unroll 8
            for (int rr = 0; rr < 16; ++rr) {
                const float hval = ((const float*)&uni[(rbase+rr)*17])[ad];
                const float* pr = (const float*)&p_lds4[rbase+rr];
                dota = fmaf(pr[wa], hval, dota);
                dotb = fmaf(pr[wb], hval, dotb);
            }
            const float mna = fmaxf(m_run_a, lm[wa]);
            const float eaa = __expf(m_run_a - mna);
            const float eba = __expf(lm[wa] - mna);
            accr_a  = fmaf(accr_a,  eaa, dota * eba);
            s_run_a = fmaf(s_run_a, eaa, ps[wa] * eba);
            m_run_a = mna;
            const float mnb = fmaxf(m_run_b, lm[wb]);
            const float eab = __expf(m_run_b - mnb);
            const float ebb = __expf(lm[wb] - mnb);
            accr_b  = fmaf(accr_b,  eab, dotb * ebb);
            s_run_b = fmaf(s_run_b, eab, ps[wb] * ebb);
            m_run_b = mnb;
        }
    }

    {
        float* pp = part + (size_t)((b * NBLK + cb) * 4 + wv) * PART_STRIDE;
        if (ad == 0) {
            pp[wa] = m_run_a; pp[4 + wa] = s_run_a;
            pp[wb] = m_run_b; pp[4 + wb] = s_run_b;
        }
        pp[8 + wa*32 + ad] = accr_a;
        pp[8 + wb*32 + ad] = accr_b;
    }
}

// ---------------- Kernel 2: merge partials + per-batch encoder head ----------------
__global__ void pe_k2(const float* __restrict__ part,
                      const float* __restrict__ cw, const float* __restrict__ cb_,
                      const float* __restrict__ cg, const float* __restrict__ cbn,
                      const float* __restrict__ ew1, const float* __restrict__ eb1,
                      const float* __restrict__ eg1, const float* __restrict__ ebn1,
                      const float* __restrict__ ew2, const float* __restrict__ eb2,
                      const float* __restrict__ eg2, const float* __restrict__ ebn2,
                      float* __restrict__ out)
{
    const int b = blockIdx.x, tid = threadIdx.x;
    const int w = tid >> 5, d = tid & 31;
    __shared__ float hs[128];
    __shared__ float cbuf[32];
    __shared__ float ebuf[256];
    __shared__ float obuf[64];

    float m = -1e30f, s = 0.f, a = 0.f;
    for (int c = 0; c < NPART; ++c) {
        const float* pp = part + (size_t)(b * NPART + c) * PART_STRIDE;
        const float mc = pp[w], sc = pp[4 + w], ac = pp[8 + w*32 + d];
        const float mn = fmaxf(m, mc);
        const float e0 = __expf(m - mn), e1v = __expf(mc - mn);
        a = fmaf(a, e0, ac * e1v);
        s = fmaf(s, e0, sc * e1v);
        m = mn;
    }
    hs[w*32 + d] = a / fmaxf(s, 1e-30f);
    const bool has = (s > 0.f);
    __syncthreads();

    if (tid < 32) {
        float acc = cb_[tid];
        for (int k = 0; k < 128; ++k) acc = fmaf(hs[k], cw[k*32 + tid], acc);
        cbuf[tid] = acc;
    }
    __syncthreads();
    {
        float mu = 0.f, sq = 0.f;
        for (int k = 0; k < 32; ++k) { float v = cbuf[k]; mu += v; sq = fmaf(v, v, sq); }
        mu *= (1.f/32);
        float var = fmaxf(sq*(1.f/32) - mu*mu, 0.f);
        const float rs = rsqrtf(var + LN_EPS);
        __syncthreads();
        if (tid < 32) {
            float v = (cbuf[tid] - mu) * rs;
            v = fmaxf(fmaf(v, cg[tid], cbn[tid]), 0.f);
            cbuf[tid] = has ? v : 0.f;
        }
    }
    __syncthreads();

    #pragma unroll
    for (int r = 0; r < 2; ++r) {
        const int o = tid + r*128;
        float acc = eb1[o];
        for (int k = 0; k < 32; ++k) acc = fmaf(cbuf[k], ew1[k*EHH + o], acc);
        ebuf[o] = acc;
    }
    __syncthreads();
    {
        float mu = 0.f, sq = 0.f;
        for (int k = 0; k < 256; ++k) { float v = ebuf[k]; mu += v; sq = fmaf(v, v, sq); }
        mu *= (1.f/256);
        float var = fmaxf(sq*(1.f/256) - mu*mu, 0.f);
        const float rs = rsqrtf(var + LN_EPS);
        __syncthreads();
        #pragma unroll
        for (int r = 0; r < 2; ++r) {
            const int o = tid + r*128;
            float v = (ebuf[o] - mu) * rs;
            ebuf[o] = fmaxf(fmaf(v, eg1[o], ebn1[o]), 0.f);
        }
    }
    __syncthreads();

    if (tid < 64) {
        float acc = eb2[tid];
        for (int k = 0; k < 256; ++k) acc = fmaf(ebuf[k], ew2[k*64 + tid], acc);
        obuf[tid] = acc;
    }
    __syncthreads();
    {
        float mu = 0.f, sq = 0.f;
        for (int k = 0; k < 64; ++k) { float v = obuf[k]; mu += v; sq = fmaf(v, v, sq); }
        mu *= (1.f/64);
        float var = fmaxf(sq*(1.f/64) - mu*mu, 0.f);
        const float rs = rsqrtf(var + LN_EPS);
        if (tid < 64) {
            float v = (obuf[tid] - mu) * rs;
            v = fmaxf(fmaf(v, eg2[tid], ebn2[tid]), 0.f);
            if (tid < 32) out[(size_t)b*32 + tid] = v;
            else          out[(size_t)BB*32 + (size_t)b*32 + (tid-32)] = v;
        }
    }
}

extern "C" void kernel_launch(void* const* d_in, const int* in_sizes, int n_in,
                              void* d_out, int out_size, void* d_ws, size_t ws_size,
                              hipStream_t stream) {
    (void)in_sizes; (void)n_in; (void)out_size; (void)ws_size;
    const float* x     = (const float*)d_in[0];
    const int*   mask  = (const int*)  d_in[1];
    const float* feat  = (const float*)d_in[2];
    const float* h_w1  = (const float*)d_in[3];
    const float* h_b1  = (const float*)d_in[4];
    const float* h_l1g = (const float*)d_in[5];
    const float* h_l1b = (const float*)d_in[6];
    const float* h_w2  = (const float*)d_in[7];
    const float* h_b2  = (const float*)d_in[8];
    const float* h_l2g = (const float*)d_in[9];
    const float* h_l2b = (const float*)d_in[10];
    const float* g_w1  = (const float*)d_in[11];
    const float* g_b1  = (const float*)d_in[12];
    const float* g_w2  = (const float*)d_in[13];
    const float* g_b2  = (const float*)d_in[14];
    const float* c_w   = (const float*)d_in[15];
    const float* c_b   = (const float*)d_in[16];
    const float* c_lg  = (const float*)d_in[17];
    const float* c_lb  = (const float*)d_in[18];
    const float* e_w1  = (const float*)d_in[19];
    const float* e_b1  = (const float*)d_in[20];
    const float* e_l1g = (const float*)d_in[21];
    const float* e_l1b = (const float*)d_in[22];
    const float* e_w2  = (const float*)d_in[23];
    const float* e_b2  = (const float*)d_in[24];
    const float* e_l2g = (const float*)d_in[25];
    const float* e_l2b = (const float*)d_in[26];

    float*  part   = (float*)d_ws;
    float*  hpre   = (float*)((char*)d_ws + HPRE_OFF);
    float4* hstat4 = (float4*)((char*)d_ws + HSTAT_OFF);
    float*  sqv    = (float*)((char*)d_ws + SQ_OFF);
    float*  out    = (float*)d_out;

    pe_k0<<<dim3(JJ / 32), dim3(256), 0, stream>>>(feat, h_w1, h_b1, hpre, hstat4);
    pe_k0s<<<dim3(1), dim3(128), 0, stream>>>(h_w1, sqv);

    dim3 g1(NBLK, BB);
    pe_k1<<<g1, dim3(256), 0, stream>>>(x, mask, hpre, hstat4, sqv,
                                        h_w1, h_l1g, h_l1b,
                                        h_w2, h_b2, h_l2g, h_l2b,
                                        g_w1, g_b1, g_w2, g_b2, part);
    pe_k2<<<dim3(BB), dim3(128), 0, stream>>>(part,
                                              c_w, c_b, c_lg, c_lb,
                                              e_w1, e_b1, e_l1g, e_l1b,
                                              e_w2, e_b2, e_l2g, e_l2b, out);
}

// Round 22
// 331.026 us; speedup vs baseline: 1.2747x; 1.2747x over previous
//
#include <hip/hip_runtime.h>
#include <hip/hip_bf16.h>
#include <math.h>

#define BB 64
#define JJ 16384
#define DD 32
#define HH 128
#define WW 4
#define EHH 256
#define CHUNK 64
#define CPB 16
#define NBLK 16              /* JJ/(CHUNK*CPB) */
#define NPART (NBLK * 4)     /* per-wave partials */
#define PART_STRIDE 136
#define LN_EPS 1e-5f
#define HPRE_OFF  (4 << 20)                 /* part: 2.23MB at 0 */
#define HSTAT_OFF (HPRE_OFF + JJ*HH*4)      /* hpre: 8.39MB */
#define SQ_OFF    (HSTAT_OFF + JJ*16)       /* hstat: 256KB */

#define COMP(q,e) ((e)==0?(q).x:((e)==1?(q).y:((e)==2?(q).z:(q).w)))

#define FMAQ(acc,B,q,f) \
  acc[B+0]=fmaf((q).x,f,acc[B+0]); acc[B+1]=fmaf((q).y,f,acc[B+1]); \
  acc[B+2]=fmaf((q).z,f,acc[B+2]); acc[B+3]=fmaf((q).w,f,acc[B+3]);

// ---- Kernel 0: hpre' = feat @ w1[1:,:] + b1  AND per-row LN1 stats ----
__global__ void pe_k0(const float* __restrict__ feat, const float* __restrict__ w1,
                      const float* __restrict__ b1,
                      float* __restrict__ hpre, float4* __restrict__ hstat4)
{
    const int tid = threadIdx.x;
    const int row = blockIdx.x * 32 + (tid >> 3);
    const int sg = tid & 7;
    float acc[16];
    #pragma unroll
    for (int o = 0; o < 16; ++o) acc[o] = 0.f;
    const float* fr = feat + (size_t)row * 32;
    const float* w1s = w1 + sg * 16;
    #pragma unroll 4
    for (int k = 0; k < 32; ++k) {
        const float f = fr[k];
        const float* wr = w1s + (k + 1) * HH;
        const float4 q0 = *(const float4*)(wr);
        const float4 q1 = *(const float4*)(wr + 4);
        const float4 q2 = *(const float4*)(wr + 8);
        const float4 q3 = *(const float4*)(wr + 12);
        FMAQ(acc,0,q0,f) FMAQ(acc,4,q1,f) FMAQ(acc,8,q2,f) FMAQ(acc,12,q3,f)
    }
    #pragma unroll
    for (int i = 0; i < 4; ++i) {
        const float4 bq = *(const float4*)(b1 + sg*16 + 4*i);
        acc[4*i+0]+=bq.x; acc[4*i+1]+=bq.y; acc[4*i+2]+=bq.z; acc[4*i+3]+=bq.w;
    }
    float s0p=0.f, q0p=0.f, q1p=0.f;
    #pragma unroll
    for (int o = 0; o < 16; ++o) {
        s0p += acc[o];
        q0p = fmaf(acc[o], acc[o], q0p);
        q1p = fmaf(acc[o], w1s[o], q1p);   // w1 row 0 (x-weights)
    }
    #pragma unroll
    for (int st = 1; st < 8; st <<= 1) {
        s0p += __shfl_xor(s0p, st, 64);
        q0p += __shfl_xor(q0p, st, 64);
        q1p += __shfl_xor(q1p, st, 64);
    }
    if (sg == 0) hstat4[row] = make_float4(s0p, q0p, q1p, 0.f);

    float4* op = (float4*)(hpre + (size_t)row * HH + sg * 16);
    op[0] = make_float4(acc[0],acc[1],acc[2],acc[3]);
    op[1] = make_float4(acc[4],acc[5],acc[6],acc[7]);
    op[2] = make_float4(acc[8],acc[9],acc[10],acc[11]);
    op[3] = make_float4(acc[12],acc[13],acc[14],acc[15]);
}

// ---- Kernel 0s: scalars S1 = Σ w1[0,:], Q2 = Σ w1[0,:]^2 ----
__global__ void pe_k0s(const float* __restrict__ w1, float* __restrict__ sq)
{
    const int t = threadIdx.x;   // 128
    float w = w1[t];
    float s = w, q = w * w;
    #pragma unroll
    for (int st = 1; st < 64; st <<= 1) {
        s += __shfl_xor(s, st, 64);
        q += __shfl_xor(q, st, 64);
    }
    __shared__ float ls[4];
    if ((t & 63) == 0) { ls[(t>>6)*2] = s; ls[(t>>6)*2+1] = q; }
    __syncthreads();
    if (t == 0) { sq[0] = ls[0] + ls[2]; sq[1] = ls[1] + ls[3]; }
}

// ---------------- Kernel 1 (R19 champion, 331us) ----------------
// w2 staged in LDS (frees L1 for the hpre stream; +54% over pre-R18),
// hk4/holds lifetime-unioned into one [CHUNK][17]-f4 region (34.8KB LDS),
// wave-independent chunk loop (zero barriers), LN1 via closed-form stats,
// per-wave online-softmax partials merged in pe_k2.
__launch_bounds__(256, 2)
__global__ void pe_k1(const float* __restrict__ x, const int* __restrict__ mask,
                      const float* __restrict__ hpre,
                      const float4* __restrict__ hstat4, const float* __restrict__ sq,
                      const float* __restrict__ w1,
                      const float* __restrict__ ln1g, const float* __restrict__ ln1b,
                      const float* __restrict__ w2, const float* __restrict__ b2,
                      const float* __restrict__ ln2g, const float* __restrict__ ln2b,
                      const float* __restrict__ gw1, const float* __restrict__ gb1,
                      const float* __restrict__ gw2, const float* __restrict__ gb2,
                      float* __restrict__ part)
{
    const int tid = threadIdx.x;
    const int cb = blockIdx.x, b = blockIdx.y;
    const int rg = tid >> 3, sg = tid & 7;
    const int r0 = rg * 2, r1 = r0 + 1;
    const int wv = tid >> 6, lane = tid & 63;

    __shared__ float4 uni[CHUNK * 17];    // hk4 (cols 0..15) / holds (cols 0..7)
    __shared__ float4 p_lds4[CHUNK];      // softmax numerators (4 heads)
    __shared__ float4 w2l[HH * 8];        // w2 staged: f4 idx = k*8 + dquad (16KB)

    const int ad = lane & 31, half = lane >> 5;
    const int wa = half, wb = half + 2;
    const int rbase = wv * 16;

    float m_run_a = -1e30f, s_run_a = 0.f, accr_a = 0.f;
    float m_run_b = -1e30f, s_run_b = 0.f, accr_b = 0.f;

    const float* w1s = w1 + sg * 16;
    const float S1v = sq[0], Q2v = sq[1];

    // ---- preload w2 into LDS (once per block) ----
    {
        const float4* w2g = (const float4*)w2;
        #pragma unroll
        for (int i = 0; i < 4; ++i) w2l[tid + i*256] = w2g[tid + i*256];
    }
    __syncthreads();

    for (int ch = 0; ch < CPB; ++ch) {
        const int jbase = (cb * CPB + ch) * CHUNK;

        // ---- stage 1: hb = hpre' + x*w1[0] (b1 already folded) ----
        float hb0[16], hb1[16];
        const float2 xq = *(const float2*)(x + (size_t)b * JJ + jbase + r0);
        {
            const float4* hp4 = (const float4*)(hpre + (size_t)jbase * HH);
            #pragma unroll
            for (int i = 0; i < 4; ++i) {
                const float4 h0q = hp4[r0*32 + sg*4 + i];
                const float4 h1q = hp4[r1*32 + sg*4 + i];
                const float4 wq = *(const float4*)(w1s + 4*i);
                hb0[4*i+0] = fmaf(wq.x, xq.x, h0q.x);
                hb0[4*i+1] = fmaf(wq.y, xq.x, h0q.y);
                hb0[4*i+2] = fmaf(wq.z, xq.x, h0q.z);
                hb0[4*i+3] = fmaf(wq.w, xq.x, h0q.w);
                hb1[4*i+0] = fmaf(wq.x, xq.y, h1q.x);
                hb1[4*i+1] = fmaf(wq.y, xq.y, h1q.y);
                hb1[4*i+2] = fmaf(wq.z, xq.y, h1q.z);
                hb1[4*i+3] = fmaf(wq.w, xq.y, h1q.w);
            }
        }
        // ---- LN1 + relu via closed-form stats (no butterfly) ----
        {
            const float4 st0 = hstat4[jbase + r0];
            const float4 st1 = hstat4[jbase + r1];
            const float mu0 = (st0.x + xq.x * S1v) * (1.f/HH);
            const float e20 = (st0.y + 2.f*xq.x*st0.z + xq.x*xq.x*Q2v) * (1.f/HH);
            const float rs0 = rsqrtf(fmaxf(e20 - mu0*mu0, 0.f) + LN_EPS);
            const float mu1 = (st1.x + xq.y * S1v) * (1.f/HH);
            const float e21 = (st1.y + 2.f*xq.y*st1.z + xq.y*xq.y*Q2v) * (1.f/HH);
            const float rs1 = rsqrtf(fmaxf(e21 - mu1*mu1, 0.f) + LN_EPS);
            #pragma unroll
            for (int q4 = 0; q4 < 4; ++q4) {
                const float4 gq = *(const float4*)(ln1g + sg*16 + q4*4);
                const float4 tq = *(const float4*)(ln1b + sg*16 + q4*4);
                hb0[q4*4+0]=fmaxf(fmaf((hb0[q4*4+0]-mu0)*rs0, gq.x, tq.x),0.f);
                hb0[q4*4+1]=fmaxf(fmaf((hb0[q4*4+1]-mu0)*rs0, gq.y, tq.y),0.f);
                hb0[q4*4+2]=fmaxf(fmaf((hb0[q4*4+2]-mu0)*rs0, gq.z, tq.z),0.f);
                hb0[q4*4+3]=fmaxf(fmaf((hb0[q4*4+3]-mu0)*rs0, gq.w, tq.w),0.f);
                hb1[q4*4+0]=fmaxf(fmaf((hb1[q4*4+0]-mu1)*rs1, gq.x, tq.x),0.f);
                hb1[q4*4+1]=fmaxf(fmaf((hb1[q4*4+1]-mu1)*rs1, gq.y, tq.y),0.f);
                hb1[q4*4+2]=fmaxf(fmaf((hb1[q4*4+2]-mu1)*rs1, gq.z, tq.z),0.f);
                hb1[q4*4+3]=fmaxf(fmaf((hb1[q4*4+3]-mu1)*rs1, gq.w, tq.w),0.f);
            }
        }

        // ---- stage 2: h(128) @ w2 -> d[sg*4 .. +3], two K-halves via uni ----
        float ac0[4] = {0.f,0.f,0.f,0.f}, ac1[4] = {0.f,0.f,0.f,0.f};
        #pragma unroll
        for (int hf2 = 0; hf2 < 2; ++hf2) {
            if ((sg >> 2) == hf2) {                 // owners publish this half
                const int sgl = sg & 3;
                #pragma unroll
                for (int o4 = 0; o4 < 4; ++o4) {
                    const int p = (sgl*4 + o4 + rg) & 15;
                    uni[r0*17 + p] = make_float4(hb0[o4*4],hb0[o4*4+1],hb0[o4*4+2],hb0[o4*4+3]);
                    uni[r1*17 + p] = make_float4(hb1[o4*4],hb1[o4*4+1],hb1[o4*4+2],hb1[o4*4+3]);
                }
            }
            // same-wave producer/consumer: DS pipe is in-order, no barrier
            #pragma unroll 4
            for (int L = 0; L < 16; ++L) {
                const int p = (L + rg) & 15;
                const float4 h0q = uni[r0*17 + p];
                const float4 h1q = uni[r1*17 + p];
                #pragma unroll
                for (int e = 0; e < 4; ++e) {
                    const float4 wq = w2l[(hf2*64 + L*4 + e)*8 + sg];
                    const float h0 = COMP(h0q,e), h1 = COMP(h1q,e);
                    ac0[0]=fmaf(h0,wq.x,ac0[0]); ac1[0]=fmaf(h1,wq.x,ac1[0]);
                    ac0[1]=fmaf(h0,wq.y,ac0[1]); ac1[1]=fmaf(h1,wq.y,ac1[1]);
                    ac0[2]=fmaf(h0,wq.z,ac0[2]); ac1[2]=fmaf(h1,wq.z,ac1[2]);
                    ac0[3]=fmaf(h0,wq.w,ac0[3]); ac1[3]=fmaf(h1,wq.w,ac1[3]);
                }
            }
        }
        {
            const float4 bq = *(const float4*)(b2 + sg*4);
            ac0[0]+=bq.x; ac0[1]+=bq.y; ac0[2]+=bq.z; ac0[3]+=bq.w;
            ac1[0]+=bq.x; ac1[1]+=bq.y; ac1[2]+=bq.z; ac1[3]+=bq.w;
        }
        // ---- LN2 + relu -> holds (cols 0..7 of uni; hk4 data dead now) ----
        {
            float s0 = ac0[0]+ac0[1]+ac0[2]+ac0[3];
            float s1 = ac1[0]+ac1[1]+ac1[2]+ac1[3];
            float q0 = ac0[0]*ac0[0]+ac0[1]*ac0[1]+ac0[2]*ac0[2]+ac0[3]*ac0[3];
            float q1 = ac1[0]*ac1[0]+ac1[1]*ac1[1]+ac1[2]*ac1[2]+ac1[3]*ac1[3];
            #pragma unroll
            for (int st = 1; st < 8; st <<= 1) {
                s0 += __shfl_xor(s0, st, 64); q0 += __shfl_xor(q0, st, 64);
                s1 += __shfl_xor(s1, st, 64); q1 += __shfl_xor(q1, st, 64);
            }
            const float mu0 = s0 * (1.f/DD);
            const float rs0 = rsqrtf(fmaxf(q0*(1.f/DD) - mu0*mu0, 0.f) + LN_EPS);
            const float mu1 = s1 * (1.f/DD);
            const float rs1 = rsqrtf(fmaxf(q1*(1.f/DD) - mu1*mu1, 0.f) + LN_EPS);
            const float4 gq = *(const float4*)(ln2g + sg*4);
            const float4 tq = *(const float4*)(ln2b + sg*4);
            uni[r0*17 + sg] = make_float4(
                fmaxf(fmaf((ac0[0]-mu0)*rs0, gq.x, tq.x),0.f),
                fmaxf(fmaf((ac0[1]-mu0)*rs0, gq.y, tq.y),0.f),
                fmaxf(fmaf((ac0[2]-mu0)*rs0, gq.z, tq.z),0.f),
                fmaxf(fmaf((ac0[3]-mu0)*rs0, gq.w, tq.w),0.f));
            uni[r1*17 + sg] = make_float4(
                fmaxf(fmaf((ac1[0]-mu1)*rs1, gq.x, tq.x),0.f),
                fmaxf(fmaf((ac1[1]-mu1)*rs1, gq.y, tq.y),0.f),
                fmaxf(fmaf((ac1[2]-mu1)*rs1, gq.z, tq.z),0.f),
                fmaxf(fmaf((ac1[3]-mu1)*rs1, gq.w, tq.w),0.f));
        }

        // ---- stage 3 (remapped): lane computes o={2sg,2sg+1} over full K=32 ----
        float g1r0[2] = {0.f, 0.f}, g1r1[2] = {0.f, 0.f};
        #pragma unroll
        for (int k4 = 0; k4 < 8; ++k4) {
            const float4 h0q = uni[r0*17 + k4];
            const float4 h1q = uni[r1*17 + k4];
            #pragma unroll
            for (int e = 0; e < 4; ++e) {
                const float2 wq = *(const float2*)(gw1 + (k4*4+e)*16 + sg*2);
                const float h0 = COMP(h0q,e), h1 = COMP(h1q,e);
                g1r0[0]=fmaf(h0,wq.x,g1r0[0]); g1r0[1]=fmaf(h0,wq.y,g1r0[1]);
                g1r1[0]=fmaf(h1,wq.x,g1r1[0]); g1r1[1]=fmaf(h1,wq.y,g1r1[1]);
            }
        }
        {
            const float2 gbq = *(const float2*)(gb1 + sg*2);
            g1r0[0]=fmaxf(g1r0[0]+gbq.x,0.f); g1r0[1]=fmaxf(g1r0[1]+gbq.y,0.f);
            g1r1[0]=fmaxf(g1r1[0]+gbq.x,0.f); g1r1[1]=fmaxf(g1r1[1]+gbq.y,0.f);
        }

        // ---- stage 4: partial over own 2 o, butterfly over sg, bias+clip ----
        float l0[4], l1[4];
        {
            const float4 w0q = *(const float4*)(gw2 + (sg*2)*4);
            const float4 w1q = *(const float4*)(gw2 + (sg*2+1)*4);
            l0[0]=fmaf(g1r0[0],w0q.x, g1r0[1]*w1q.x);
            l0[1]=fmaf(g1r0[0],w0q.y, g1r0[1]*w1q.y);
            l0[2]=fmaf(g1r0[0],w0q.z, g1r0[1]*w1q.z);
            l0[3]=fmaf(g1r0[0],w0q.w, g1r0[1]*w1q.w);
            l1[0]=fmaf(g1r1[0],w0q.x, g1r1[1]*w1q.x);
            l1[1]=fmaf(g1r1[0],w0q.y, g1r1[1]*w1q.y);
            l1[2]=fmaf(g1r1[0],w0q.z, g1r1[1]*w1q.z);
            l1[3]=fmaf(g1r1[0],w0q.w, g1r1[1]*w1q.w);
            #pragma unroll
            for (int st = 1; st < 8; st <<= 1) {
                #pragma unroll
                for (int w = 0; w < 4; ++w) {
                    l0[w] += __shfl_xor(l0[w], st, 64);
                    l1[w] += __shfl_xor(l1[w], st, 64);
                }
            }
            const float4 gbq = *(const float4*)gb2;
            l0[0] = fminf(fmaxf(l0[0]+gbq.x, -10.f), 10.f);
            l0[1] = fminf(fmaxf(l0[1]+gbq.y, -10.f), 10.f);
            l0[2] = fminf(fmaxf(l0[2]+gbq.z, -10.f), 10.f);
            l0[3] = fminf(fmaxf(l0[3]+gbq.w, -10.f), 10.f);
            l1[0] = fminf(fmaxf(l1[0]+gbq.x, -10.f), 10.f);
            l1[1] = fminf(fmaxf(l1[1]+gbq.y, -10.f), 10.f);
            l1[2] = fminf(fmaxf(l1[2]+gbq.z, -10.f), 10.f);
            l1[3] = fminf(fmaxf(l1[3]+gbq.w, -10.f), 10.f);
        }

        // ---- wave-local masked max (stages 8/16/32) ----
        const int2 mq = *(const int2*)(mask + (size_t)b * JJ + jbase + r0);
        const float mk0 = mq.x ? 1.f : 0.f, mk1 = mq.y ? 1.f : 0.f;
        float lm[4];
        #pragma unroll
        for (int w = 0; w < 4; ++w)
            lm[w] = fmaxf(mk0 > 0.f ? l0[w] : -1e30f,
                          mk1 > 0.f ? l1[w] : -1e30f);
        #pragma unroll
        for (int st = 8; st < 64; st <<= 1) {
            #pragma unroll
            for (int w = 0; w < 4; ++w)
                lm[w] = fmaxf(lm[w], __shfl_xor(lm[w], st, 64));
        }

        // ---- p = mask*exp(l - m_wave); publish (sg==0); wave-local sums ----
        float ps[4];
        {
            float p0v[4], p1v[4];
            #pragma unroll
            for (int w = 0; w < 4; ++w) {
                p0v[w] = mk0 * __expf(fminf(l0[w] - lm[w], 0.f));
                p1v[w] = mk1 * __expf(fminf(l1[w] - lm[w], 0.f));
                ps[w] = p0v[w] + p1v[w];
            }
            if (sg == 0) {
                p_lds4[r0] = make_float4(p0v[0],p0v[1],p0v[2],p0v[3]);
                p_lds4[r1] = make_float4(p1v[0],p1v[1],p1v[2],p1v[3]);
            }
            #pragma unroll
            for (int st = 8; st < 64; st <<= 1) {
                #pragma unroll
                for (int w = 0; w < 4; ++w) ps[w] += __shfl_xor(ps[w], st, 64);
            }
        }

        // ---- wave-local weighted-sum accumulate with online merge ----
        {
            float dota = 0.f, dotb = 0.f;
            #pragma unroll 8
            for (int rr = 0; rr < 16; ++rr) {
                const float hval = ((const float*)&uni[(rbase+rr)*17])[ad];
                const float* pr = (const float*)&p_lds4[rbase+rr];
                dota = fmaf(pr[wa], hval, dota);
                dotb = fmaf(pr[wb], hval, dotb);
            }
            const float mna = fmaxf(m_run_a, lm[wa]);
            const float eaa = __expf(m_run_a - mna);
            const float eba = __expf(lm[wa] - mna);
            accr_a  = fmaf(accr_a,  eaa, dota * eba);
            s_run_a = fmaf(s_run_a, eaa, ps[wa] * eba);
            m_run_a = mna;
            const float mnb = fmaxf(m_run_b, lm[wb]);
            const float eab = __expf(m_run_b - mnb);
            const float ebb = __expf(lm[wb] - mnb);
            accr_b  = fmaf(accr_b,  eab, dotb * ebb);
            s_run_b = fmaf(s_run_b, eab, ps[wb] * ebb);
            m_run_b = mnb;
        }
    }

    {
        float* pp = part + (size_t)((b * NBLK + cb) * 4 + wv) * PART_STRIDE;
        if (ad == 0) {
            pp[wa] = m_run_a; pp[4 + wa] = s_run_a;
            pp[wb] = m_run_b; pp[4 + wb] = s_run_b;
        }
        pp[8 + wa*32 + ad] = accr_a;
        pp[8 + wb*32 + ad] = accr_b;
    }
}

// ---------------- Kernel 2: merge partials + per-batch encoder head ----------------
__global__ void pe_k2(const float* __restrict__ part,
                      const float* __restrict__ cw, const float* __restrict__ cb_,
                      const float* __restrict__ cg, const float* __restrict__ cbn,
                      const float* __restrict__ ew1, const float* __restrict__ eb1,
                      const float* __restrict__ eg1, const float* __restrict__ ebn1,
                      const float* __restrict__ ew2, const float* __restrict__ eb2,
                      const float* __restrict__ eg2, const float* __restrict__ ebn2,
                      float* __restrict__ out)
{
    const int b = blockIdx.x, tid = threadIdx.x;
    const int w = tid >> 5, d = tid & 31;
    __shared__ float hs[128];
    __shared__ float cbuf[32];
    __shared__ float ebuf[256];
    __shared__ float obuf[64];

    float m = -1e30f, s = 0.f, a = 0.f;
    for (int c = 0; c < NPART; ++c) {
        const float* pp = part + (size_t)(b * NPART + c) * PART_STRIDE;
        const float mc = pp[w], sc = pp[4 + w], ac = pp[8 + w*32 + d];
        const float mn = fmaxf(m, mc);
        const float e0 = __expf(m - mn), e1v = __expf(mc - mn);
        a = fmaf(a, e0, ac * e1v);
        s = fmaf(s, e0, sc * e1v);
        m = mn;
    }
    hs[w*32 + d] = a / fmaxf(s, 1e-30f);
    const bool has = (s > 0.f);
    __syncthreads();

    if (tid < 32) {
        float acc = cb_[tid];
        for (int k = 0; k < 128; ++k) acc = fmaf(hs[k], cw[k*32 + tid], acc);
        cbuf[tid] = acc;
    }
    __syncthreads();
    {
        float mu = 0.f, sq = 0.f;
        for (int k = 0; k < 32; ++k) { float v = cbuf[k]; mu += v; sq = fmaf(v, v, sq); }
        mu *= (1.f/32);
        float var = fmaxf(sq*(1.f/32) - mu*mu, 0.f);
        const float rs = rsqrtf(var + LN_EPS);
        __syncthreads();
        if (tid < 32) {
            float v = (cbuf[tid] - mu) * rs;
            v = fmaxf(fmaf(v, cg[tid], cbn[tid]), 0.f);
            cbuf[tid] = has ? v : 0.f;
        }
    }
    __syncthreads();

    #pragma unroll
    for (int r = 0; r < 2; ++r) {
        const int o = tid + r*128;
        float acc = eb1[o];
        for (int k = 0; k < 32; ++k) acc = fmaf(cbuf[k], ew1[k*EHH + o], acc);
        ebuf[o] = acc;
    }
    __syncthreads();
    {
        float mu = 0.f, sq = 0.f;
        for (int k = 0; k < 256; ++k) { float v = ebuf[k]; mu += v; sq = fmaf(v, v, sq); }
        mu *= (1.f/256);
        float var = fmaxf(sq*(1.f/256) - mu*mu, 0.f);
        const float rs = rsqrtf(var + LN_EPS);
        __syncthreads();
        #pragma unroll
        for (int r = 0; r < 2; ++r) {
            const int o = tid + r*128;
            float v = (ebuf[o] - mu) * rs;
            ebuf[o] = fmaxf(fmaf(v, eg1[o], ebn1[o]), 0.f);
        }
    }
    __syncthreads();

    if (tid < 64) {
        float acc = eb2[tid];
        for (int k = 0; k < 256; ++k) acc = fmaf(ebuf[k], ew2[k*64 + tid], acc);
        obuf[tid] = acc;
    }
    __syncthreads();
    {
        float mu = 0.f, sq = 0.f;
        for (int k = 0; k < 64; ++k) { float v = obuf[k]; mu += v; sq = fmaf(v, v, sq); }
        mu *= (1.f/64);
        float var = fmaxf(sq*(1.f/64) - mu*mu, 0.f);
        const float rs = rsqrtf(var + LN_EPS);
        if (tid < 64) {
            float v = (obuf[tid] - mu) * rs;
            v = fmaxf(fmaf(v, eg2[tid], ebn2[tid]), 0.f);
            if (tid < 32) out[(size_t)b*32 + tid] = v;
            else          out[(size_t)BB*32 + (size_t)b*32 + (tid-32)] = v;
        }
    }
}

extern "C" void kernel_launch(void* const* d_in, const int* in_sizes, int n_in,
                              void* d_out, int out_size, void* d_ws, size_t ws_size,
                              hipStream_t stream) {
    (void)in_sizes; (void)n_in; (void)out_size; (void)ws_size;
    const float* x     = (const float*)d_in[0];
    const int*   mask  = (const int*)  d_in[1];
    const float* feat  = (const float*)d_in[2];
    const float* h_w1  = (const float*)d_in[3];
    const float* h_b1  = (const float*)d_in[4];
    const float* h_l1g = (const float*)d_in[5];
    const float* h_l1b = (const float*)d_in[6];
    const float* h_w2  = (const float*)d_in[7];
    const float* h_b2  = (const float*)d_in[8];
    const float* h_l2g = (const float*)d_in[9];
    const float* h_l2b = (const float*)d_in[10];
    const float* g_w1  = (const float*)d_in[11];
    const float* g_b1  = (const float*)d_in[12];
    const float* g_w2  = (const float*)d_in[13];
    const float* g_b2  = (const float*)d_in[14];
    const float* c_w   = (const float*)d_in[15];
    const float* c_b   = (const float*)d_in[16];
    const float* c_lg  = (const float*)d_in[17];
    const float* c_lb  = (const float*)d_in[18];
    const float* e_w1  = (const float*)d_in[19];
    const float* e_b1  = (const float*)d_in[20];
    const float* e_l1g = (const float*)d_in[21];
    const float* e_l1b = (const float*)d_in[22];
    const float* e_w2  = (const float*)d_in[23];
    const float* e_b2  = (const float*)d_in[24];
    const float* e_l2g = (const float*)d_in[25];
    const float* e_l2b = (const float*)d_in[26];

    float*  part   = (float*)d_ws;
    float*  hpre   = (float*)((char*)d_ws + HPRE_OFF);
    float4* hstat4 = (float4*)((char*)d_ws + HSTAT_OFF);
    float*  sqv    = (float*)((char*)d_ws + SQ_OFF);
    float*  out    = (float*)d_out;

    pe_k0<<<dim3(JJ / 32), dim3(256), 0, stream>>>(feat, h_w1, h_b1, hpre, hstat4);
    pe_k0s<<<dim3(1), dim3(128), 0, stream>>>(h_w1, sqv);

    dim3 g1(NBLK, BB);
    pe_k1<<<g1, dim3(256), 0, stream>>>(x, mask, hpre, hstat4, sqv,
                                        h_w1, h_l1g, h_l1b,
                                        h_w2, h_b2, h_l2g, h_l2b,
                                        g_w1, g_b1, g_w2, g_b2, part);
    pe_k2<<<dim3(BB), dim3(128), 0, stream>>>(part,
                                              c_w, c_b, c_lg, c_lb,
                                              e_w1, e_b1, e_l1g, e_l1b,
                                              e_w2, e_b2, e_l2g, e_l2b, out);
}